// Round 5
// baseline (984.892 us; speedup 1.0000x reference)
//
#include <hip/hip_runtime.h>
#include <hip/hip_cooperative_groups.h>
#include <math.h>

namespace cg = cooperative_groups;

// MultiBoxLoss (SSD) on MI355X.
// R5 (= R4 fixed): single cooperative persistent kernel. Keys
// (ce bits | argmax<<31) live in VGPRs across all phases:
// zero-ws -> key+pos-loss+hist1(12b LDS) -> pick1 -> hist2(12b, rare global
// atomics) -> pick2 -> hist3(7b) -> pick3 -> neg-select -> final reduce.
// R4's compile error (global-from-global call) fixed by making the body a
// __device__ function.

#define MAXB 64
#define NS 1024
#define NB1 4096  // bits [30:19]
#define NB2 4096  // bits [18:7]
#define NB3 128   // bits [6:0]

struct Accum {
  int row_np[MAXB];
  unsigned int row_thr[MAXB];
  int row_need_eq[MAXB];
  int row_eq_taken[MAXB];
  float f_loc[NS], f_clsp[NS], f_perr[NS], f_se0[NS], f_se1[NS], f_clsn[NS];
  int i_pcor[NS], i_ncor[NS], i_ntot[NS];
};

__device__ __forceinline__ float iou_f(float4 g, float4 an) {
  float ax0 = an.x - an.z * 0.5f, ay0 = an.y - an.w * 0.5f;
  float ax1 = an.x + an.z * 0.5f, ay1 = an.y + an.w * 0.5f;
  float ltx = fmaxf(g.x, ax0), lty = fmaxf(g.y, ay0);
  float rbx = fminf(g.z, ax1), rby = fminf(g.w, ay1);
  float w = fmaxf(rbx - ltx, 0.f), h = fmaxf(rby - lty, 0.f);
  float inter = w * h;
  float area_g = (g.z - g.x) * (g.w - g.y);
  float area_a = (ax1 - ax0) * (ay1 - ay0);
  return inter / (area_g + area_a - inter);
}

__device__ __forceinline__ float sl1(float x) {
  float ax = fabsf(x);
  return ax < 1.f ? 0.5f * x * x : ax - 0.5f;
}

// Parallel pick: find the bin (scanning from top) where the cumulative
// count (from the top) crosses kr; store prefix bits and residual rank.
__device__ void pick_row(const unsigned int* __restrict__ hrow, int nb,
                         int shift, int pass0, int b, int A, Accum* acc,
                         unsigned int* lh, unsigned int* cs,
                         unsigned int* sb_bin, int* sb_kr) {
  int tid = threadIdx.x;
  for (int i = tid; i < nb; i += 256) lh[i] = hrow[i];
  __syncthreads();
  int kr0;
  if (pass0) {
    int k = 3 * acc->row_np[b];
    if (k < 10) k = 10;
    if (k > A - 1) k = A - 1;
    kr0 = k;
  } else {
    kr0 = acc->row_need_eq[b];
  }
  int per = (nb + 255) >> 8;
  int lo = tid * per;
  int hi = min(nb, lo + per);
  unsigned int my = 0;
  for (int i = lo; i < hi; ++i) my += lh[i];
  // suffix-sum over the 256 per-thread chunk counts
  unsigned int v = my;
  cs[tid] = v;
  __syncthreads();
  for (int o = 1; o < 256; o <<= 1) {
    unsigned int add = (tid + o < 256) ? cs[tid + o] : 0u;
    __syncthreads();
    v += add;
    cs[tid] = v;
    __syncthreads();
  }
  unsigned int incl = cs[tid];          // count in my chunk + all above
  unsigned int above = incl - my;       // strictly above my chunk
  if ((int)above < kr0 && kr0 <= (int)incl) {
    int kk = kr0 - (int)above;
    for (int i = hi - 1; i >= lo; --i) {
      int c = (int)lh[i];
      if (kk <= c) {
        *sb_bin = (unsigned int)i;
        *sb_kr = kk;
        break;
      }
      kk -= c;
    }
  }
  __syncthreads();
  if (tid == 0) {
    acc->row_thr[b] |= (*sb_bin) << shift;
    acc->row_need_eq[b] = *sb_kr;
  }
  __syncthreads();
}

template <int K>
__device__ void k_all_body(const float* __restrict__ loc_pred,
                           const float* __restrict__ conf,
                           const float* __restrict__ gt,
                           const float* __restrict__ anchors,
                           Accum* __restrict__ acc,
                           unsigned int* __restrict__ g1,
                           unsigned int* __restrict__ g2,
                           unsigned int* __restrict__ g3, int A,
                           float* __restrict__ out) {
  cg::grid_group grd = cg::this_grid();
  __shared__ unsigned int lh[NB1];  // hist / pick scratch (16KB)
  __shared__ unsigned int cs[256];
  __shared__ unsigned int sb_bin;
  __shared__ int sb_kr;
  __shared__ float smf[5][4];
  __shared__ int smi[2][4];

  int tid = threadIdx.x;
  int bid = blockIdx.x;
  int nblk = gridDim.x;
  int bpr = nblk / MAXB;  // blocks per row
  int b = bid / bpr;      // batch row
  int sl = bid % bpr;     // slice within row
  int lane = tid & 63, wv = tid >> 6;
  int slot = bid & (NS - 1);

  // ---- Ph0: zero workspace (ws is poisoned 0xAA by harness) ----
  {
    int* p = (int*)acc;
    int n0 = (int)(sizeof(Accum) / 4);
    int gt0 = bid * 256 + tid, gs = nblk * 256;
    for (int i = gt0; i < n0; i += gs) p[i] = 0;
    for (int i = gt0; i < MAXB * NB1; i += gs) g1[i] = 0u;
    for (int i = gt0; i < MAXB * NB2; i += gs) g2[i] = 0u;
    for (int i = gt0; i < MAXB * NB3; i += gs) g3[i] = 0u;
  }
  grd.sync();

  // ---- Ph1: keys (registers), positive losses, pass-1 histogram ----
  unsigned int key[K];
  float4 g4 = reinterpret_cast<const float4*>(gt)[b];
  const float4* conf4 = reinterpret_cast<const float4*>(conf);
  const float4* anc4 = reinterpret_cast<const float4*>(anchors);
  const float4* loc4 = reinterpret_cast<const float4*>(loc_pred);
  int abase = sl * (256 * K);
  long long cbase = ((long long)b * A + abase) >> 1;  // float4 units

  float loc_s = 0.f, clsp = 0.f, perr = 0.f, se0 = 0.f, se1 = 0.f;
  int pcnt = 0, pcor = 0;

#pragma unroll
  for (int j = 0; j < K / 2; ++j) {
    float4 cc = conf4[cbase + tid + j * 256];
    int a0 = abase + 2 * (tid + j * 256);
#pragma unroll
    for (int h = 0; h < 2; ++h) {
      int a = a0 + h;
      float c0 = h ? cc.z : cc.x;
      float c1 = h ? cc.w : cc.y;
      float4 an = anc4[a];
      float ov = iou_f(g4, an);
      unsigned int kk = 0u;
      if (ov <= 0.3f) {
        float m = fmaxf(c0, c1);
        float s = logf(expf(c0 - m) + expf(c1 - m));
        kk = __float_as_uint((m - c0) + s);
      }
      if (c1 > c0) kk |= 0x80000000u;
      key[2 * j + h] = kk;
      if (ov >= 0.6f) {
        float4 lp = loc4[(long long)b * A + a];
        float gcx = (g4.x + g4.z) * 0.5f, gcy = (g4.y + g4.w) * 0.5f;
        float gw = g4.z - g4.x, gh = g4.w - g4.y;
        float t0 = (gcx - an.x) / (0.1f * an.z);
        float t1 = (gcy - an.y) / (0.1f * an.w);
        float t2 = logf(gw / an.z) / 0.2f;
        float t3 = logf(gh / an.w) / 0.2f;
        loc_s += sl1(lp.x - t0) + sl1(lp.y - t1) + sl1(lp.z - t2) +
                 sl1(lp.w - t3);
        float m = fmaxf(c0, c1);
        float s = logf(expf(c0 - m) + expf(c1 - m));
        clsp += (m - c1) + s;
        pcnt += 1;
        pcor += (c1 > c0) ? 1 : 0;
        float dcx = an.x + lp.x * 0.1f * an.z;
        float dcy = an.y + lp.y * 0.1f * an.w;
        float dw = an.z * expf(lp.z * 0.2f);
        float dh = an.w * expf(lp.w * 0.2f);
        float dx0 = dcx - dw * 0.5f, dy0 = dcy - dh * 0.5f;
        float ex = (g4.x - dx0) * 255.f, ey = (g4.y - dy0) * 255.f;
        perr += sqrtf(ex * ex + ey * ey);
        se0 += fabsf(g4.z - (dx0 + dw));
        se1 += fabsf(g4.w - (dy0 + dh));
      }
    }
  }

  // block-reduce positive stats -> slot atomics
  {
    float fv[5] = {loc_s, clsp, perr, se0, se1};
    int iv[2] = {pcnt, pcor};
#pragma unroll
    for (int q = 0; q < 5; ++q) {
      float v = fv[q];
#pragma unroll
      for (int o = 32; o > 0; o >>= 1) v += __shfl_down(v, o, 64);
      if (lane == 0) smf[q][wv] = v;
    }
#pragma unroll
    for (int q = 0; q < 2; ++q) {
      int v = iv[q];
#pragma unroll
      for (int o = 32; o > 0; o >>= 1) v += __shfl_down(v, o, 64);
      if (lane == 0) smi[q][wv] = v;
    }
    __syncthreads();
    if (tid == 0) {
      float L = 0, C = 0, P = 0, S0 = 0, S1 = 0;
      int PC = 0, COR = 0;
      for (int w2 = 0; w2 < 4; ++w2) {
        L += smf[0][w2]; C += smf[1][w2]; P += smf[2][w2];
        S0 += smf[3][w2]; S1 += smf[4][w2];
        PC += smi[0][w2]; COR += smi[1][w2];
      }
      if (PC > 0) {
        atomicAdd(&acc->row_np[b], PC);
        atomicAdd(&acc->f_loc[slot], L);
        atomicAdd(&acc->f_clsp[slot], C);
        atomicAdd(&acc->f_perr[slot], P);
        atomicAdd(&acc->f_se0[slot], S0);
        atomicAdd(&acc->f_se1[slot], S1);
        atomicAdd(&acc->i_pcor[slot], COR);
      }
    }
    __syncthreads();
  }

  // pass-1 histogram: bits [30:19], LDS-aggregated
  for (int i = tid; i < NB1; i += 256) lh[i] = 0u;
  __syncthreads();
#pragma unroll
  for (int j = 0; j < K; ++j)
    atomicAdd(&lh[(key[j] & 0x7FFFFFFFu) >> 19], 1u);
  __syncthreads();
  for (int i = tid; i < NB1; i += 256)
    if (lh[i]) atomicAdd(&g1[b * NB1 + i], lh[i]);
  grd.sync();

  // ---- Ph2: pick1 ----
  if (bid < MAXB)
    pick_row(g1 + bid * NB1, NB1, 19, 1, bid, A, acc, lh, cs, &sb_bin, &sb_kr);
  grd.sync();

  // ---- Ph3: hist2 (bits [18:7]) — only prefix-matching keys (rare) ----
  {
    unsigned int thr1 = acc->row_thr[b];
#pragma unroll
    for (int j = 0; j < K; ++j) {
      unsigned int k31 = key[j] & 0x7FFFFFFFu;
      if ((k31 & 0x7FF80000u) == thr1)
        atomicAdd(&g2[b * NB2 + ((k31 >> 7) & 0xFFFu)], 1u);
    }
  }
  grd.sync();

  // ---- Ph4: pick2 ----
  if (bid < MAXB)
    pick_row(g2 + bid * NB2, NB2, 7, 0, bid, A, acc, lh, cs, &sb_bin, &sb_kr);
  grd.sync();

  // ---- Ph5: hist3 (bits [6:0]) ----
  {
    unsigned int thr2 = acc->row_thr[b];
#pragma unroll
    for (int j = 0; j < K; ++j) {
      unsigned int k31 = key[j] & 0x7FFFFFFFu;
      if ((k31 & 0x7FFFFF80u) == thr2)
        atomicAdd(&g3[b * NB3 + (k31 & 0x7Fu)], 1u);
    }
  }
  grd.sync();

  // ---- Ph6: pick3 ----
  if (bid < MAXB)
    pick_row(g3 + bid * NB3, NB3, 0, 0, bid, A, acc, lh, cs, &sb_bin, &sb_kr);
  grd.sync();

  // ---- Ph7: negative selection from registers ----
  {
    unsigned int thr = acc->row_thr[b];
    int need = acc->row_need_eq[b];
    float cls = 0.f;
    int ncnt = 0, ncor = 0;
#pragma unroll
    for (int j = 0; j < K; ++j) {
      unsigned int k31 = key[j] & 0x7FFFFFFFu;
      bool s = false;
      if (k31 > thr) {
        s = true;
      } else if (k31 == thr) {
        int ord = atomicAdd(&acc->row_eq_taken[b], 1);
        if (ord < need) s = true;
      }
      if (s) {
        cls += __uint_as_float(k31);
        ncnt += 1;
        ncor += (int)((key[j] >> 31) ^ 1u);
      }
    }
    {
      float v = cls;
#pragma unroll
      for (int o = 32; o > 0; o >>= 1) v += __shfl_down(v, o, 64);
      if (lane == 0) smf[0][wv] = v;
    }
    {
      int v = ncnt;
#pragma unroll
      for (int o = 32; o > 0; o >>= 1) v += __shfl_down(v, o, 64);
      if (lane == 0) smi[0][wv] = v;
    }
    {
      int v = ncor;
#pragma unroll
      for (int o = 32; o > 0; o >>= 1) v += __shfl_down(v, o, 64);
      if (lane == 0) smi[1][wv] = v;
    }
    __syncthreads();
    if (tid == 0) {
      float C = smf[0][0] + smf[0][1] + smf[0][2] + smf[0][3];
      int NC = smi[0][0] + smi[0][1] + smi[0][2] + smi[0][3];
      int COR = smi[1][0] + smi[1][1] + smi[1][2] + smi[1][3];
      if (NC > 0) {
        atomicAdd(&acc->f_clsn[slot], C);
        atomicAdd(&acc->i_ntot[slot], NC);
        atomicAdd(&acc->i_ncor[slot], COR);
      }
    }
  }
  grd.sync();

  // ---- Ph8: final reduce (block 0) ----
  if (bid == 0) {
    __shared__ float sm[256];
    int t = tid;
    float vals[10];
    float s;
    s = 0; for (int i = t; i < NS; i += 256) s += acc->f_loc[i];  vals[0] = s;
    s = 0; for (int i = t; i < NS; i += 256) s += acc->f_clsp[i]; vals[1] = s;
    s = 0; for (int i = t; i < NS; i += 256) s += acc->f_perr[i]; vals[2] = s;
    s = 0; for (int i = t; i < NS; i += 256) s += acc->f_se0[i];  vals[3] = s;
    s = 0; for (int i = t; i < NS; i += 256) s += acc->f_se1[i];  vals[4] = s;
    s = 0; for (int i = t; i < NS; i += 256) s += acc->f_clsn[i]; vals[5] = s;
    s = 0; for (int i = t; i < NS; i += 256) s += (float)acc->i_pcor[i]; vals[6] = s;
    s = 0; for (int i = t; i < NS; i += 256) s += (float)acc->i_ncor[i]; vals[7] = s;
    s = 0; for (int i = t; i < NS; i += 256) s += (float)acc->i_ntot[i]; vals[8] = s;
    s = 0; for (int i = t; i < MAXB; i += 256) s += (float)acc->row_np[i]; vals[9] = s;
    float tot[10];
    for (int q = 0; q < 10; ++q) {
      sm[t] = vals[q];
      __syncthreads();
      for (int o = 128; o > 0; o >>= 1) {
        if (t < o) sm[t] += sm[t + o];
        __syncthreads();
      }
      tot[q] = sm[0];
      __syncthreads();
    }
    if (t == 0) {
      float N = tot[9];
      float Nf = fmaxf(N, 1.f);
      out[0] = tot[0] / (Nf * 4.f);
      float wsum = N + tot[8] * (1.f / 3.f);
      out[1] = (tot[1] + tot[5] * (1.f / 3.f)) / wsum;
      out[2] = tot[6] / fmaxf(N, 1.f);
      out[3] = tot[7] / fmaxf(tot[8], 1.f);
      out[4] = tot[2] / Nf;
      out[5] = tot[3] / Nf * 255.f;
      out[6] = tot[4] / Nf * 255.f;
      out[7] = N;
    }
  }
}

template <int K>
__global__ __launch_bounds__(256, 4) void k_all_full(
    const float* __restrict__ loc_pred, const float* __restrict__ conf,
    const float* __restrict__ gt, const float* __restrict__ anchors,
    Accum* __restrict__ acc, unsigned int* __restrict__ g1,
    unsigned int* __restrict__ g2, unsigned int* __restrict__ g3, int A,
    float* __restrict__ out) {
  k_all_body<K>(loc_pred, conf, gt, anchors, acc, g1, g2, g3, A, out);
}

extern "C" void kernel_launch(void* const* d_in, const int* in_sizes, int n_in,
                              void* d_out, int out_size, void* d_ws,
                              size_t ws_size, hipStream_t stream) {
  (void)n_in; (void)out_size; (void)ws_size;
  const float* loc = (const float*)d_in[0];
  const float* conf = (const float*)d_in[1];
  const float* gt = (const float*)d_in[2];
  const float* anchors = (const float*)d_in[3];
  int A = in_sizes[3] / 4;  // 65536
  float* out = (float*)d_out;

  char* w = (char*)d_ws;
  Accum* acc = (Accum*)w;
  size_t off = (sizeof(Accum) + 255) & ~(size_t)255;
  unsigned int* g1 = (unsigned int*)(w + off);
  off += (size_t)MAXB * NB1 * 4;
  unsigned int* g2 = (unsigned int*)(w + off);
  off += (size_t)MAXB * NB2 * 4;
  unsigned int* g3 = (unsigned int*)(w + off);

  void* args[] = {(void*)&loc, (void*)&conf, (void*)&gt, (void*)&anchors,
                  (void*)&acc, (void*)&g1,   (void*)&g2, (void*)&g3,
                  (void*)&A,   (void*)&out};

  int occ16 = 0;
  (void)hipOccupancyMaxActiveBlocksPerMultiprocessor(
      &occ16, (const void*)k_all_full<16>, 256, 0);
  if (occ16 >= 4) {
    (void)hipLaunchCooperativeKernel((void*)k_all_full<16>, dim3(64 * 16),
                                     dim3(256), args, 0, stream);
  } else {
    (void)hipLaunchCooperativeKernel((void*)k_all_full<32>, dim3(64 * 8),
                                     dim3(256), args, 0, stream);
  }
}

// Round 6
// 173.362 us; speedup vs baseline: 5.6811x; 5.6811x over previous
//
#include <hip/hip_runtime.h>
#include <math.h>

// MultiBoxLoss (SSD) on MI355X.
// R6: back to multi-kernel (R5's cooperative grid.sync costs ~100us each on
// 8 XCDs — 9 syncs = 880us of spin, VALUBusy 1.6%). R3 skeleton compressed:
//   init -> main(keys + pos losses + 8-bit hist1 fused)
//        -> h2 (12-bit hist of hist1-boundary keys)
//        -> h3 (11-bit hist of hist2-boundary keys)
//        -> neg (selection) -> final.
// No pick kernels: each block recomputes the pick chain from the small global
// histograms (256/4096/2048 bins) with shfl suffix-scans. 6 dispatches total.

#define MAXB 64
#define NS 1024
#define NB1 256   // key bits [30:23]
#define NB2 4096  // key bits [22:11]
#define NB3 2048  // key bits [10:0]

struct Accum {
  int row_np[MAXB];
  int row_eq_taken[MAXB];
  float f_loc[NS], f_clsp[NS], f_perr[NS], f_se0[NS], f_se1[NS], f_clsn[NS];
  int i_pcor[NS], i_ncor[NS], i_ntot[NS];
};

__device__ __forceinline__ float iou_f(float4 g, float4 an) {
  float ax0 = an.x - an.z * 0.5f, ay0 = an.y - an.w * 0.5f;
  float ax1 = an.x + an.z * 0.5f, ay1 = an.y + an.w * 0.5f;
  float ltx = fmaxf(g.x, ax0), lty = fmaxf(g.y, ay0);
  float rbx = fminf(g.z, ax1), rby = fminf(g.w, ay1);
  float w = fmaxf(rbx - ltx, 0.f), h = fmaxf(rby - lty, 0.f);
  float inter = w * h;
  float area_g = (g.z - g.x) * (g.w - g.y);
  float area_a = (ax1 - ax0) * (ay1 - ay0);
  return inter / (area_g + area_a - inter);
}

__device__ __forceinline__ float sl1(float x) {
  float ax = fabsf(x);
  return ax < 1.f ? 0.5f * x * x : ax - 0.5f;
}

// Block-wide pick over an NB-bin global histogram: find bin where the
// from-the-top cumulative count crosses kr_in; return (bin, residual rank).
// Uses wave shfl suffix-scan; 2 barriers. All threads get the result.
template <int NB>
__device__ uint2 pick_hist(const unsigned int* __restrict__ h, int kr_in,
                           unsigned int* s_wsum,
                           volatile unsigned int* s_bin,
                           volatile unsigned int* s_kr) {
  int tid = threadIdx.x, lane = tid & 63, wv = tid >> 6;
  constexpr int PER = NB / 256;
  unsigned int loc[PER];
  unsigned int my = 0;
#pragma unroll
  for (int i = 0; i < PER; ++i) {
    loc[i] = h[tid * PER + i];
    my += loc[i];
  }
  // suffix-inclusive scan: incl(t) = sum over threads t..255 (higher bins)
  unsigned int v = my;
#pragma unroll
  for (int o = 1; o < 64; o <<= 1) {
    unsigned int tv = __shfl_down(v, o, 64);
    if (lane + o < 64) v += tv;
  }
  if (lane == 0) s_wsum[wv] = v;
  __syncthreads();
  unsigned int off = 0;
  for (int w2 = wv + 1; w2 < 4; ++w2) off += s_wsum[w2];
  unsigned int vw = v;
  // broadcast wave-suffix from my lane (shfl gave lane-local suffix)
  unsigned int incl = vw + off;
  unsigned int above = incl - my;
  if ((int)above < kr_in && kr_in <= (int)incl) {
    int kk = kr_in - (int)above;
    for (int i = PER - 1; i >= 0; --i) {
      int c = (int)loc[i];
      if (kk <= c) {
        *s_bin = (unsigned int)(tid * PER + i);
        *s_kr = (unsigned int)kk;
        break;
      }
      kk -= c;
    }
  }
  __syncthreads();
  uint2 r;
  r.x = *s_bin;
  r.y = *s_kr;
  __syncthreads();
  return r;
}

__device__ __forceinline__ int row_k(const Accum* acc, int b, int A) {
  int k = 3 * acc->row_np[b];
  if (k < 10) k = 10;
  if (k > A - 1) k = A - 1;
  return k;
}

__global__ __launch_bounds__(256) void k_init(Accum* acc, unsigned int* g1,
                                              unsigned int* g2,
                                              unsigned int* g3) {
  int idx = blockIdx.x * 256 + threadIdx.x;
  int stride = gridDim.x * 256;
  int n0 = (int)(sizeof(Accum) / 4);
  int* p = (int*)acc;
  for (int i = idx; i < n0; i += stride) p[i] = 0;
  for (int i = idx; i < MAXB * NB1; i += stride) g1[i] = 0u;
  for (int i = idx; i < MAXB * NB2; i += stride) g2[i] = 0u;
  for (int i = idx; i < MAXB * NB3; i += stride) g3[i] = 0u;
}

// keys + positive losses + fused 8-bit hist1. grid (A/4096, B).
__global__ __launch_bounds__(256) void k_main(
    const float* __restrict__ loc_pred, const float* __restrict__ conf,
    const float* __restrict__ gt, const float* __restrict__ anchors,
    Accum* __restrict__ acc, unsigned int* __restrict__ g1,
    unsigned int* __restrict__ keys, int A) {
  int b = blockIdx.y;
  int tid = threadIdx.x;
  int lane = tid & 63, wv = tid >> 6;
  __shared__ unsigned int hist[4][NB1];  // wave-private replicas (4 KB)
  __shared__ float smf[5][4];
  __shared__ int smi[2][4];
  for (int i = tid; i < 4 * NB1; i += 256) ((unsigned int*)hist)[i] = 0u;
  __syncthreads();

  float4 g4 = reinterpret_cast<const float4*>(gt)[b];
  const float4* conf4 = reinterpret_cast<const float4*>(conf);
  const float4* anc4 = reinterpret_cast<const float4*>(anchors);
  const float4* loc4 = reinterpret_cast<const float4*>(loc_pred);
  int abase = blockIdx.x * 4096;
  long long cbase = ((long long)b * A + abase) >> 1;  // float4 units
  uint2* keys2 = reinterpret_cast<uint2*>(keys);

  float loc_s = 0.f, clsp = 0.f, perr = 0.f, se0 = 0.f, se1 = 0.f;
  int pcnt = 0, pcor = 0;

#pragma unroll
  for (int j = 0; j < 8; ++j) {
    float4 cc = conf4[cbase + tid + j * 256];
    int a0 = abase + 2 * (tid + j * 256);
    uint2 kv;
#pragma unroll
    for (int h = 0; h < 2; ++h) {
      int a = a0 + h;
      float c0 = h ? cc.z : cc.x;
      float c1 = h ? cc.w : cc.y;
      float4 an = anc4[a];
      float ov = iou_f(g4, an);
      unsigned int kk = 0u;
      if (ov <= 0.3f) {
        float m = fmaxf(c0, c1);
        float s = logf(expf(c0 - m) + expf(c1 - m));
        kk = __float_as_uint((m - c0) + s);
      }
      if (c1 > c0) kk |= 0x80000000u;
      if (h) kv.y = kk; else kv.x = kk;
      atomicAdd(&hist[wv][(kk & 0x7FFFFFFFu) >> 23], 1u);
      if (ov >= 0.6f) {
        float4 lp = loc4[(long long)b * A + a];
        float gcx = (g4.x + g4.z) * 0.5f, gcy = (g4.y + g4.w) * 0.5f;
        float gw = g4.z - g4.x, gh = g4.w - g4.y;
        float t0 = (gcx - an.x) / (0.1f * an.z);
        float t1 = (gcy - an.y) / (0.1f * an.w);
        float t2 = logf(gw / an.z) / 0.2f;
        float t3 = logf(gh / an.w) / 0.2f;
        loc_s += sl1(lp.x - t0) + sl1(lp.y - t1) + sl1(lp.z - t2) +
                 sl1(lp.w - t3);
        float m = fmaxf(c0, c1);
        float s = logf(expf(c0 - m) + expf(c1 - m));
        clsp += (m - c1) + s;
        pcnt += 1;
        pcor += (c1 > c0) ? 1 : 0;
        float dcx = an.x + lp.x * 0.1f * an.z;
        float dcy = an.y + lp.y * 0.1f * an.w;
        float dw = an.z * expf(lp.z * 0.2f);
        float dh = an.w * expf(lp.w * 0.2f);
        float dx0 = dcx - dw * 0.5f, dy0 = dcy - dh * 0.5f;
        float ex = (g4.x - dx0) * 255.f, ey = (g4.y - dy0) * 255.f;
        perr += sqrtf(ex * ex + ey * ey);
        se0 += fabsf(g4.z - (dx0 + dw));
        se1 += fabsf(g4.w - (dy0 + dh));
      }
    }
    keys2[cbase + tid + j * 256] = kv;
  }

  // flush hist1
  __syncthreads();
  for (int i = tid; i < NB1; i += 256) {
    unsigned int h = hist[0][i] + hist[1][i] + hist[2][i] + hist[3][i];
    if (h) atomicAdd(&g1[b * NB1 + i], h);
  }

  // block-reduce positive stats -> slot atomics
  float fv[5] = {loc_s, clsp, perr, se0, se1};
  int iv[2] = {pcnt, pcor};
#pragma unroll
  for (int q = 0; q < 5; ++q) {
    float v = fv[q];
#pragma unroll
    for (int o = 32; o > 0; o >>= 1) v += __shfl_down(v, o, 64);
    if (lane == 0) smf[q][wv] = v;
  }
#pragma unroll
  for (int q = 0; q < 2; ++q) {
    int v = iv[q];
#pragma unroll
    for (int o = 32; o > 0; o >>= 1) v += __shfl_down(v, o, 64);
    if (lane == 0) smi[q][wv] = v;
  }
  __syncthreads();
  if (tid == 0) {
    float L = 0, C = 0, P = 0, S0 = 0, S1 = 0;
    int PC = 0, COR = 0;
    for (int w2 = 0; w2 < 4; ++w2) {
      L += smf[0][w2]; C += smf[1][w2]; P += smf[2][w2];
      S0 += smf[3][w2]; S1 += smf[4][w2];
      PC += smi[0][w2]; COR += smi[1][w2];
    }
    if (PC > 0) {
      int slot = (blockIdx.y * gridDim.x + blockIdx.x) & (NS - 1);
      atomicAdd(&acc->row_np[b], PC);
      atomicAdd(&acc->f_loc[slot], L);
      atomicAdd(&acc->f_clsp[slot], C);
      atomicAdd(&acc->f_perr[slot], P);
      atomicAdd(&acc->f_se0[slot], S0);
      atomicAdd(&acc->f_se1[slot], S1);
      atomicAdd(&acc->i_pcor[slot], COR);
    }
  }
}

// load this block's 4096 keys (4 x uint4 per thread)
__device__ __forceinline__ void load_keys16(const unsigned int* __restrict__ keys,
                                            int b, int A, unsigned int* kk) {
  long long base4 = (((long long)b * A) >> 2) + blockIdx.x * 1024 + threadIdx.x;
  const uint4* k4 = reinterpret_cast<const uint4*>(keys);
#pragma unroll
  for (int j = 0; j < 4; ++j) {
    uint4 v = k4[base4 + j * 256];
    kk[4 * j + 0] = v.x; kk[4 * j + 1] = v.y;
    kk[4 * j + 2] = v.z; kk[4 * j + 3] = v.w;
  }
}

// hist2: 12-bit histogram (bits [22:11]) of keys matching the hist1 pick.
__global__ __launch_bounds__(256) void k_h2(const unsigned int* __restrict__ keys,
                                            const unsigned int* __restrict__ g1,
                                            unsigned int* __restrict__ g2,
                                            Accum* __restrict__ acc, int A) {
  int b = blockIdx.y;
  __shared__ unsigned int s_wsum[4];
  __shared__ unsigned int s_bin, s_kr;
  uint2 p1 = pick_hist<NB1>(g1 + b * NB1, row_k(acc, b, A), s_wsum, &s_bin, &s_kr);
  unsigned int kk[16];
  load_keys16(keys, b, A, kk);
#pragma unroll
  for (int j = 0; j < 16; ++j) {
    unsigned int k31 = kk[j] & 0x7FFFFFFFu;
    if ((k31 >> 23) == p1.x)
      atomicAdd(&g2[b * NB2 + ((k31 >> 11) & 0xFFFu)], 1u);
  }
}

// hist3: 11-bit histogram (bits [10:0]) of keys matching picks 1+2.
__global__ __launch_bounds__(256) void k_h3(const unsigned int* __restrict__ keys,
                                            const unsigned int* __restrict__ g1,
                                            const unsigned int* __restrict__ g2,
                                            unsigned int* __restrict__ g3,
                                            Accum* __restrict__ acc, int A) {
  int b = blockIdx.y;
  __shared__ unsigned int s_wsum[4];
  __shared__ unsigned int s_bin, s_kr;
  uint2 p1 = pick_hist<NB1>(g1 + b * NB1, row_k(acc, b, A), s_wsum, &s_bin, &s_kr);
  uint2 p2 = pick_hist<NB2>(g2 + b * NB2, (int)p1.y, s_wsum, &s_bin, &s_kr);
  unsigned int pref20 = (p1.x << 12) | p2.x;
  unsigned int kk[16];
  load_keys16(keys, b, A, kk);
#pragma unroll
  for (int j = 0; j < 16; ++j) {
    unsigned int k31 = kk[j] & 0x7FFFFFFFu;
    if ((k31 >> 11) == pref20) atomicAdd(&g3[b * NB3 + (k31 & 0x7FFu)], 1u);
  }
}

// negative selection.
__global__ __launch_bounds__(256) void k_neg(const unsigned int* __restrict__ keys,
                                             const unsigned int* __restrict__ g1,
                                             const unsigned int* __restrict__ g2,
                                             const unsigned int* __restrict__ g3,
                                             Accum* __restrict__ acc, int A) {
  int b = blockIdx.y;
  int tid = threadIdx.x;
  int lane = tid & 63, wv = tid >> 6;
  __shared__ unsigned int s_wsum[4];
  __shared__ unsigned int s_bin, s_kr;
  __shared__ float smf[4];
  __shared__ int smi[2][4];
  uint2 p1 = pick_hist<NB1>(g1 + b * NB1, row_k(acc, b, A), s_wsum, &s_bin, &s_kr);
  uint2 p2 = pick_hist<NB2>(g2 + b * NB2, (int)p1.y, s_wsum, &s_bin, &s_kr);
  uint2 p3 = pick_hist<NB3>(g3 + b * NB3, (int)p2.y, s_wsum, &s_bin, &s_kr);
  unsigned int thr = (p1.x << 23) | (p2.x << 11) | p3.x;
  int need = (int)p3.y;

  unsigned int kk[16];
  load_keys16(keys, b, A, kk);
  float cls = 0.f;
  int ncnt = 0, ncor = 0;
#pragma unroll
  for (int j = 0; j < 16; ++j) {
    unsigned int k31 = kk[j] & 0x7FFFFFFFu;
    bool s = false;
    if (k31 > thr) {
      s = true;
    } else if (k31 == thr) {
      int ord = atomicAdd(&acc->row_eq_taken[b], 1);
      if (ord < need) s = true;
    }
    if (s) {
      cls += __uint_as_float(k31);
      ncnt += 1;
      ncor += (int)((kk[j] >> 31) ^ 1u);
    }
  }
  {
    float v = cls;
#pragma unroll
    for (int o = 32; o > 0; o >>= 1) v += __shfl_down(v, o, 64);
    if (lane == 0) smf[wv] = v;
  }
  {
    int v = ncnt;
#pragma unroll
    for (int o = 32; o > 0; o >>= 1) v += __shfl_down(v, o, 64);
    if (lane == 0) smi[0][wv] = v;
  }
  {
    int v = ncor;
#pragma unroll
    for (int o = 32; o > 0; o >>= 1) v += __shfl_down(v, o, 64);
    if (lane == 0) smi[1][wv] = v;
  }
  __syncthreads();
  if (tid == 0) {
    float C = smf[0] + smf[1] + smf[2] + smf[3];
    int NC = smi[0][0] + smi[0][1] + smi[0][2] + smi[0][3];
    int COR = smi[1][0] + smi[1][1] + smi[1][2] + smi[1][3];
    if (NC > 0) {
      int slot = (blockIdx.y * gridDim.x + blockIdx.x) & (NS - 1);
      atomicAdd(&acc->f_clsn[slot], C);
      atomicAdd(&acc->i_ntot[slot], NC);
      atomicAdd(&acc->i_ncor[slot], COR);
    }
  }
}

__global__ __launch_bounds__(256) void k_final(const Accum* __restrict__ acc,
                                               float* __restrict__ out, int B) {
  __shared__ float sm[256];
  int t = threadIdx.x;
  float vals[10];
  float s;
  s = 0; for (int i = t; i < NS; i += 256) s += acc->f_loc[i];  vals[0] = s;
  s = 0; for (int i = t; i < NS; i += 256) s += acc->f_clsp[i]; vals[1] = s;
  s = 0; for (int i = t; i < NS; i += 256) s += acc->f_perr[i]; vals[2] = s;
  s = 0; for (int i = t; i < NS; i += 256) s += acc->f_se0[i];  vals[3] = s;
  s = 0; for (int i = t; i < NS; i += 256) s += acc->f_se1[i];  vals[4] = s;
  s = 0; for (int i = t; i < NS; i += 256) s += acc->f_clsn[i]; vals[5] = s;
  s = 0; for (int i = t; i < NS; i += 256) s += (float)acc->i_pcor[i]; vals[6] = s;
  s = 0; for (int i = t; i < NS; i += 256) s += (float)acc->i_ncor[i]; vals[7] = s;
  s = 0; for (int i = t; i < NS; i += 256) s += (float)acc->i_ntot[i]; vals[8] = s;
  s = 0; for (int i = t; i < B;  i += 256) s += (float)acc->row_np[i]; vals[9] = s;
  float tot[10];
  for (int q = 0; q < 10; ++q) {
    sm[t] = vals[q];
    __syncthreads();
    for (int o = 128; o > 0; o >>= 1) {
      if (t < o) sm[t] += sm[t + o];
      __syncthreads();
    }
    tot[q] = sm[0];
    __syncthreads();
  }
  if (t == 0) {
    float N = tot[9];
    float Nf = fmaxf(N, 1.f);
    out[0] = tot[0] / (Nf * 4.f);
    float wsum = N + tot[8] * (1.f / 3.f);
    out[1] = (tot[1] + tot[5] * (1.f / 3.f)) / wsum;
    out[2] = tot[6] / fmaxf(N, 1.f);
    out[3] = tot[7] / fmaxf(tot[8], 1.f);
    out[4] = tot[2] / Nf;
    out[5] = tot[3] / Nf * 255.f;
    out[6] = tot[4] / Nf * 255.f;
    out[7] = N;
  }
}

extern "C" void kernel_launch(void* const* d_in, const int* in_sizes, int n_in,
                              void* d_out, int out_size, void* d_ws,
                              size_t ws_size, hipStream_t stream) {
  (void)n_in; (void)out_size; (void)ws_size;
  const float* loc = (const float*)d_in[0];
  const float* conf = (const float*)d_in[1];
  const float* gt = (const float*)d_in[2];
  const float* anchors = (const float*)d_in[3];
  int B = in_sizes[2] / 4;  // 64
  int A = in_sizes[3] / 4;  // 65536
  float* out = (float*)d_out;

  char* w = (char*)d_ws;
  Accum* acc = (Accum*)w;
  size_t off = (sizeof(Accum) + 255) & ~(size_t)255;
  unsigned int* g1 = (unsigned int*)(w + off);
  off += (size_t)MAXB * NB1 * 4;
  unsigned int* g2 = (unsigned int*)(w + off);
  off += (size_t)MAXB * NB2 * 4;
  unsigned int* g3 = (unsigned int*)(w + off);
  off += (size_t)MAXB * NB3 * 4;
  off = (off + 255) & ~(size_t)255;
  unsigned int* keys = (unsigned int*)(w + off);

  dim3 grid(A / 4096, B);
  k_init<<<128, 256, 0, stream>>>(acc, g1, g2, g3);
  k_main<<<grid, 256, 0, stream>>>(loc, conf, gt, anchors, acc, g1, keys, A);
  k_h2<<<grid, 256, 0, stream>>>(keys, g1, g2, acc, A);
  k_h3<<<grid, 256, 0, stream>>>(keys, g1, g2, g3, acc, A);
  k_neg<<<grid, 256, 0, stream>>>(keys, g1, g2, g3, acc, A);
  k_final<<<1, 256, 0, stream>>>(acc, out, B);
}